// Round 10
// baseline (480.432 us; speedup 1.0000x reference)
//
#include <hip/hip_runtime.h>
#include <math.h>

#define B 2
#define T 4096
#define D 1024
#define DH 32
#define TNB 32        // 128-row tiles per batch
#define NBLK 528      // TNB*(TNB+1)/2 causal tile pairs
#define NK 12         // per-chunk candidates kept (safety margin over 8)
#define CPR (32*NK)   // candidates per row = 384

typedef __bf16 bf16x8 __attribute__((ext_vector_type(8)));
typedef float f32x4 __attribute__((ext_vector_type(4)));

// ---------------- K_conv: src -> (hi, lo) bf16 split (2048 elems/block) -------
__global__ __launch_bounds__(256) void conv_kernel(const float* __restrict__ x,
        __bf16* __restrict__ xhi, __bf16* __restrict__ xlo)
{
    int i = (blockIdx.x * 256 + threadIdx.x) << 3;     // 8 floats/thread
    float4 a = *(const float4*)(x + i);
    float4 c = *(const float4*)(x + i + 4);
    float av[8] = {a.x, a.y, a.z, a.w, c.x, c.y, c.z, c.w};
    __bf16 h[8], l[8];
    #pragma unroll
    for (int j = 0; j < 8; ++j) {
        h[j] = (__bf16)av[j];
        l[j] = (__bf16)(av[j] - (float)h[j]);
    }
    *(float4*)(xhi + i) = *(float4*)h;
    *(float4*)(xlo + i) = *(float4*)l;
}

// ---------------- K0: per-batch column sums (for the t=0 row) ----------------
__global__ void mean_kernel(const float* __restrict__ x, float* __restrict__ meansum)
{
    int gid  = blockIdx.x;           // B * 4 dblk * 16 tch = 128 blocks
    int b    = gid >> 6;
    int rem  = gid & 63;
    int dblk = rem >> 4;
    int tch  = rem & 15;
    int d = dblk * 256 + threadIdx.x;
    const float* xp = x + (b * T + tch * 256) * D + d;
    float s = 0.f;
    #pragma unroll 8
    for (int it = 0; it < 256; ++it) s += xp[it * D];
    atomicAdd(&meansum[(b << 10) + d], s);
}

// ---------------- K1: q/k projection as split-bf16 MFMA GEMM -----------------
__global__ __launch_bounds__(256) void qk_mfma_kernel(
        const __bf16* __restrict__ xhi, const __bf16* __restrict__ xlo,
        const __bf16* __restrict__ Whi, const __bf16* __restrict__ Wlo,
        float* __restrict__ qo, float* __restrict__ ko)
{
    __shared__ __align__(16) __bf16 stg[15360];
    __bf16* sAhi = stg;            // 128 x 40
    __bf16* sAlo = stg + 5120;
    __bf16* sBhi = stg + 10240;    // 64 x 40
    __bf16* sBlo = stg + 12800;

    int tid = threadIdx.x;
    int m0 = blockIdx.x << 7;
    int w = tid >> 6, lane = tid & 63;
    int fr = lane & 15, fq = lane >> 4;

    int arow = tid >> 1, ah = tid & 1;      // A staging: 2 chunks of 16 bf16
    int brow = tid >> 2, bq = tid & 3;      // B staging: 4 chunks of 8 bf16

    const __bf16* gAh = xhi + (size_t)(m0 + arow) * D + ah * 16;
    const __bf16* gAl = xlo + (size_t)(m0 + arow) * D + ah * 16;
    const __bf16* gBh = Whi + brow * D + bq * 8;
    const __bf16* gBl = Wlo + brow * D + bq * 8;

    f32x4 acc[2][4];
    #pragma unroll
    for (int i = 0; i < 2; ++i)
        #pragma unroll
        for (int j = 0; j < 4; ++j) acc[i][j] = (f32x4){0.f, 0.f, 0.f, 0.f};

    float4 a0 = *(const float4*)(gAh);
    float4 a1 = *(const float4*)(gAh + 8);
    float4 a2 = *(const float4*)(gAl);
    float4 a3 = *(const float4*)(gAl + 8);
    float4 b0 = *(const float4*)(gBh);
    float4 b1 = *(const float4*)(gBl);

    int sa = arow * 40 + ah * 16;
    int sb = brow * 40 + bq * 8;

    for (int kc = 0; kc < 32; ++kc) {
        __syncthreads();
        *(float4*)(sAhi + sa) = a0;  *(float4*)(sAhi + sa + 8) = a1;
        *(float4*)(sAlo + sa) = a2;  *(float4*)(sAlo + sa + 8) = a3;
        *(float4*)(sBhi + sb) = b0;  *(float4*)(sBlo + sb) = b1;
        __syncthreads();
        if (kc + 1 < 32) {
            int k0 = (kc + 1) << 5;
            a0 = *(const float4*)(gAh + k0);
            a1 = *(const float4*)(gAh + k0 + 8);
            a2 = *(const float4*)(gAl + k0);
            a3 = *(const float4*)(gAl + k0 + 8);
            b0 = *(const float4*)(gBh + k0);
            b1 = *(const float4*)(gBl + k0);
        }
        bf16x8 fah[2], fal[2], fbh[4], fbl[4];
        #pragma unroll
        for (int i = 0; i < 2; ++i) {
            int r = (w << 5) + i * 16 + fr;
            fah[i] = *(const bf16x8*)(sAhi + r * 40 + fq * 8);
            fal[i] = *(const bf16x8*)(sAlo + r * 40 + fq * 8);
        }
        #pragma unroll
        for (int j = 0; j < 4; ++j) {
            int r = j * 16 + fr;
            fbh[j] = *(const bf16x8*)(sBhi + r * 40 + fq * 8);
            fbl[j] = *(const bf16x8*)(sBlo + r * 40 + fq * 8);
        }
        #pragma unroll
        for (int i = 0; i < 2; ++i)
            #pragma unroll
            for (int j = 0; j < 4; ++j) {
                acc[i][j] = __builtin_amdgcn_mfma_f32_16x16x32_bf16(fah[i], fbh[j], acc[i][j], 0, 0, 0);
                acc[i][j] = __builtin_amdgcn_mfma_f32_16x16x32_bf16(fah[i], fbl[j], acc[i][j], 0, 0, 0);
                acc[i][j] = __builtin_amdgcn_mfma_f32_16x16x32_bf16(fal[i], fbh[j], acc[i][j], 0, 0, 0);
            }
    }
    // writeout: C layout col=lane&15, row=fq*4+reg
    #pragma unroll
    for (int i = 0; i < 2; ++i) {
        int grow0 = m0 + (w << 5) + i * 16 + (fq << 2);
        #pragma unroll
        for (int j = 0; j < 4; ++j) {
            int gn = j * 16 + fr;
            float* dst = (gn < 32) ? (qo + grow0 * DH + gn)
                                   : (ko + grow0 * DH + gn - 32);
            dst[0]      = acc[i][j][0];
            dst[DH]     = acc[i][j][1];
            dst[2 * DH] = acc[i][j][2];
            dst[3 * DH] = acc[i][j][3];
        }
    }
}

// ---------------- K2: hi-only bf16 MFMA sim GEMM, BARRIER-FREE K-loop --------
// Fragments loaded directly from global (L1/L2 provide reuse: the 4 fq-groups
// of a wave share cachelines). Register ping-pong keeps 8 loads in flight
// during each 16-MFMA burst. LDS holds only the 64x129 score buffer.
__global__ __launch_bounds__(256, 3) void topk_mfma_kernel(
        const __bf16* __restrict__ xhi,
        float* __restrict__ pvals, int* __restrict__ pidx)
{
    __shared__ __align__(16) float Sbuf[64 * 129];     // 33024 B (scores only)

    int tid = threadIdx.x;
    int b = blockIdx.x / NBLK;
    int l = blockIdx.x - b * NBLK;
    int rt = (int)((sqrtf(8.f * l + 1.f) - 1.f) * 0.5f);
    while ((rt + 1) * (rt + 2) / 2 <= l) ++rt;
    while (rt * (rt + 1) / 2 > l) --rt;
    int ct = l - rt * (rt + 1) / 2;
    int r0 = rt << 7, c0 = ct << 7;
    int base = b * T;

    int w = tid >> 6, lane = tid & 63;
    int wr = (w >> 1) << 6, wc = (w & 1) << 6;
    bool active = !(rt == ct && w == 1);   // diag block, fully non-causal quadrant
    int fr = lane & 15, fq = lane >> 4;    // fragment: row-in-tile, k-quad

    f32x4 acc[4][4];
    #pragma unroll
    for (int i = 0; i < 4; ++i)
        #pragma unroll
        for (int j = 0; j < 4; ++j) acc[i][j] = (f32x4){0.f, 0.f, 0.f, 0.f};

    if (active) {
        const __bf16* pA = xhi + (size_t)(base + r0 + wr + fr) * D + fq * 8;
        const __bf16* pB = xhi + (size_t)(base + c0 + wc + fr) * D + fq * 8;
        bf16x8 a0[4], b0[4], a1[4], b1[4];
        #pragma unroll
        for (int i = 0; i < 4; ++i) {
            a0[i] = *(const bf16x8*)(pA + i * 16 * D);
            b0[i] = *(const bf16x8*)(pB + i * 16 * D);
        }
        for (int kc = 0; kc < 32; kc += 2) {
            int k1 = (kc + 1) << 5;
            #pragma unroll
            for (int i = 0; i < 4; ++i) {          // prefetch kc+1 while MFMA kc
                a1[i] = *(const bf16x8*)(pA + i * 16 * D + k1);
                b1[i] = *(const bf16x8*)(pB + i * 16 * D + k1);
            }
            #pragma unroll
            for (int i = 0; i < 4; ++i)
                #pragma unroll
                for (int j = 0; j < 4; ++j)
                    acc[i][j] = __builtin_amdgcn_mfma_f32_16x16x32_bf16(a0[i], b0[j], acc[i][j], 0, 0, 0);
            if (kc + 2 < 32) {
                int k2 = (kc + 2) << 5;
                #pragma unroll
                for (int i = 0; i < 4; ++i) {      // prefetch kc+2 while MFMA kc+1
                    a0[i] = *(const bf16x8*)(pA + i * 16 * D + k2);
                    b0[i] = *(const bf16x8*)(pB + i * 16 * D + k2);
                }
            }
            #pragma unroll
            for (int i = 0; i < 4; ++i)
                #pragma unroll
                for (int j = 0; j < 4; ++j)
                    acc[i][j] = __builtin_amdgcn_mfma_f32_16x16x32_bf16(a1[i], b1[j], acc[i][j], 0, 0, 0);
        }
    }

    int cr = fq << 2, cc = fr;             // C layout: col=lane&15, row=fq*4+reg
    #pragma unroll
    for (int phase = 0; phase < 2; ++phase) {
        __syncthreads();                   // prior scan done / all waves ready
        if ((w >> 1) == phase) {           // waves owning rows [phase*64, +64)
            #pragma unroll
            for (int i = 0; i < 4; ++i)
                #pragma unroll
                for (int j = 0; j < 4; ++j) {
                    float* sp = Sbuf + (i * 16 + cr) * 129 + wc + j * 16 + cc;
                    sp[0]       = acc[i][j][0];
                    sp[129]     = acc[i][j][1];
                    sp[2 * 129] = acc[i][j][2];
                    sp[3 * 129] = acc[i][j][3];
                }
        }
        __syncthreads();
        if (tid < 64) {                    // per-row top-12, 8-wide batched loads
            int gt = r0 + (phase << 6) + tid;
            int cmax = gt - c0;
            if (cmax > 128) cmax = 128;
            if (cmax < 0) cmax = 0;
            float tv[NK]; int ti[NK];
            #pragma unroll
            for (int i = 0; i < NK; ++i) { tv[i] = -INFINITY; ti[i] = -1; }
            float vmin = -INFINITY; int minp = 0;
            const float* Srow = Sbuf + tid * 129;
            for (int cb = 0; cb < cmax; cb += 8) {
                float v[8];
                #pragma unroll
                for (int j = 0; j < 8; ++j) v[j] = Srow[cb + j];   // 8 loads in flight
                #pragma unroll
                for (int j = 0; j < 8; ++j) {
                    int c = cb + j;
                    float vv = v[j];
                    if (c < cmax && vv > vmin) {
                        tv[minp] = vv; ti[minp] = c0 + c;
                        vmin = tv[0]; minp = 0;
                        #pragma unroll
                        for (int i = 1; i < NK; ++i)
                            if (tv[i] < vmin) { vmin = tv[i]; minp = i; }
                    }
                }
            }
            int ob = (base + gt) * CPR + ct * NK;
            #pragma unroll
            for (int i = 0; i < NK; ++i) { pvals[ob + i] = tv[i]; pidx[ob + i] = ti[i]; }
        }
    }
}

// ---------------- K3a: wave-per-row selection (barrier-free) ------------------
__global__ __launch_bounds__(256) void select_kernel(const float* __restrict__ x,
        const float* __restrict__ q, const float* __restrict__ k,
        const float* __restrict__ pvals, const int* __restrict__ pidx,
        float* __restrict__ selw, int* __restrict__ selg)
{
    int tid = threadIdx.x;
    int w = tid >> 6, lane = tid & 63;
    int rid = (blockIdx.x << 2) + w;         // global row b*T+t
    int b = rid >> 12, t = rid & (T - 1);
    int ncand = NK * ((t + 127) >> 7);

    // candidate loads (all in flight)
    float cv[6]; int ci[6];
    #pragma unroll
    for (int u = 0; u < 6; ++u) {
        int cid = lane + (u << 6);
        bool val = cid < ncand;
        cv[u] = val ? pvals[(size_t)rid * CPR + cid] : -INFINITY;
        ci[u] = val ? pidx[(size_t)rid * CPR + cid] : -1;
    }
    // prefetch xt fragments (independent of merge)
    const float* xt = x + (size_t)rid * D;
    float4 xt4[4];
    #pragma unroll
    for (int c = 0; c < 4; ++c)
        xt4[c] = *(const float4*)(xt + (c << 8) + (lane << 2));

    // butterfly merge -> approx top-12 (identical logic/tie-breaks)
    float sv[NK]; int si[NK];
    #pragma unroll
    for (int i = 0; i < NK; ++i) {
        float mv = cv[0]; int mi = ci[0];
        #pragma unroll
        for (int u = 1; u < 6; ++u)
            if (cv[u] > mv || (cv[u] == mv && ci[u] < mi)) { mv = cv[u]; mi = ci[u]; }
        #pragma unroll
        for (int off = 32; off >= 1; off >>= 1) {
            float ov = __shfl_xor(mv, off);
            int   oi = __shfl_xor(mi, off);
            if (ov > mv || (ov == mv && oi < mi)) { mv = ov; mi = oi; }
        }
        sv[i] = mv; si[i] = mi;
        #pragma unroll
        for (int u = 0; u < 6; ++u)
            if (cv[u] == mv && ci[u] == mi) cv[u] = -INFINITY;
    }

    // exact fp32 re-rank: 4 batches of 3 candidates, loads batched in flight
    float ex[NK];
    #pragma unroll
    for (int batch = 0; batch < 4; ++batch) {
        float4 rv[3][4];
        #pragma unroll
        for (int s = 0; s < 3; ++s) {
            int i = batch * 3 + s;
            int sj = si[i];
            const float* xj = x + (size_t)((b << 12) + (sj >= 0 ? sj : 0)) * D;
            #pragma unroll
            for (int c = 0; c < 4; ++c)
                rv[s][c] = *(const float4*)(xj + (c << 8) + (lane << 2));
        }
        #pragma unroll
        for (int s = 0; s < 3; ++s) {
            float ss = 0.f;
            #pragma unroll
            for (int c = 0; c < 4; ++c)
                ss += xt4[c].x * rv[s][c].x + xt4[c].y * rv[s][c].y
                    + xt4[c].z * rv[s][c].z + xt4[c].w * rv[s][c].w;
            ex[batch * 3 + s] = ss;
        }
    }
    // shuffle-reduce all 12 (independent chains pipeline)
    #pragma unroll
    for (int i = 0; i < NK; ++i) {
        float ssum = ex[i];
        #pragma unroll
        for (int off = 32; off >= 1; off >>= 1) ssum += __shfl_xor(ssum, off);
        ex[i] = (si[i] >= 0) ? ssum : -INFINITY;
    }

    // exact top-8 (tie-break: lower index) — every lane computes identically
    float bv[8]; int bi[8];
    #pragma unroll
    for (int r = 0; r < 8; ++r) {
        int mp = 0;
        #pragma unroll
        for (int i = 1; i < NK; ++i) {
            bool better = (ex[i] > ex[mp]) ||
                          (ex[i] == ex[mp] && si[i] >= 0 &&
                           (si[mp] < 0 || si[i] < si[mp]));
            if (better) mp = i;
        }
        bv[r] = ex[mp]; bi[r] = si[mp];
        ex[mp] = -INFINITY;
    }

    // scores: lanes 8i..8i+7 compute dot(q[t], k[sel_i])
    int i8 = lane >> 3, e = lane & 7;
    bool v8 = bv[i8] > -1e37f;
    int g8 = v8 ? bi[i8] : 0;
    float4 qv = *(const float4*)(q + (size_t)rid * DH + (e << 2));
    float4 kv = *(const float4*)(k + (size_t)((b << 12) + g8) * DH + (e << 2));
    float p = qv.x * kv.x + qv.y * kv.y + qv.z * kv.z + qv.w * kv.w;
    p += __shfl_xor(p, 1); p += __shfl_xor(p, 2); p += __shfl_xor(p, 4);
    p *= 0.17677669529663687f;               // 1/sqrt(32)

    float sc[8];
    #pragma unroll
    for (int i = 0; i < 8; ++i) sc[i] = __shfl(p, i << 3);

    float m = -INFINITY; int cnt = 0;
    #pragma unroll
    for (int i = 0; i < 8; ++i)
        if (bv[i] > -1e37f) { ++cnt; if (sc[i] > m) m = sc[i]; }

    float wgt[8]; float Z = 0.f;
    #pragma unroll
    for (int i = 0; i < 8; ++i) {
        bool val = bv[i] > -1e37f;
        wgt[i] = val ? expf(sc[i] - m) : 0.f;
        Z += wgt[i];
    }
    float invZ = (cnt > 0) ? 1.f / Z : 0.f;

    if (lane < 8) {
        selw[(rid << 3) + lane] = wgt[lane] * invZ;
        int gg = (bv[lane] > -1e37f) ? ((b << 12) + bi[lane]) : (b << 12);
        if (cnt == 0 && lane == 0) gg = -1;  // uniform-attention flag (t==0)
        selg[(rid << 3) + lane] = gg;
    }
}

// ---------------- K3b: wave-per-row streaming message + gelu epilogue --------
__global__ __launch_bounds__(256) void msg_kernel(const float* __restrict__ x,
        const float* __restrict__ meansum,
        const float* __restrict__ selw, const int* __restrict__ selg,
        const float* __restrict__ gain, const float* __restrict__ bias,
        const float* __restrict__ plm, const float* __restrict__ pls,
        float* __restrict__ out)
{
    int tid = threadIdx.x;
    int w = tid >> 6, lane = tid & 63;
    int rid = (blockIdx.x << 2) + w;         // global row b*T+t
    int b = rid >> 12;

    float mix   = 1.f / (1.f + expf(-plm[0]));
    float scale = log1pf(expf(pls[0])) + 0.01f;
    const float onemix = 1.f - mix;

    float wgt[8]; int g[8];
    #pragma unroll
    for (int i = 0; i < 8; ++i) {
        wgt[i] = selw[(rid << 3) + i];
        g[i]   = selg[(rid << 3) + i];
    }
    bool uniform = (g[0] < 0);
    if (uniform) g[0] = b << 12;             // safe address, weight is 0

    const float* xt = x + (size_t)rid * D;
    float* ot = out + (size_t)rid * D;

    #pragma unroll 2
    for (int seg = 0; seg < 4; ++seg) {
        int d0 = (seg << 8) + (lane << 2);
        float4 xv = *(const float4*)(xt + d0);
        float4 g4 = *(const float4*)(gain + d0);
        float4 b4 = *(const float4*)(bias + d0);
        float4 msg;
        if (uniform) {
            float4 ms = *(const float4*)(meansum + (b << 10) + d0);
            msg.x = ms.x * (1.f / (float)T); msg.y = ms.y * (1.f / (float)T);
            msg.z = ms.z * (1.f / (float)T); msg.w = ms.w * (1.f / (float)T);
        } else {
            msg = (float4){0.f, 0.f, 0.f, 0.f};
            #pragma unroll
            for (int i = 0; i < 8; ++i) {
                float4 rv = *(const float4*)(x + (size_t)g[i] * D + d0);
                msg.x += wgt[i] * rv.x; msg.y += wgt[i] * rv.y;
                msg.z += wgt[i] * rv.z; msg.w += wgt[i] * rv.w;
            }
        }
        float zi[4] = {
            (mix * xv.x + onemix * msg.x) * g4.x + b4.x,
            (mix * xv.y + onemix * msg.y) * g4.y + b4.y,
            (mix * xv.z + onemix * msg.z) * g4.z + b4.z,
            (mix * xv.w + onemix * msg.w) * g4.w + b4.w };
        float4 o4;
        o4.x = 0.5f * zi[0] * (1.f + erff(zi[0] * 0.70710678118654752f)) * scale;
        o4.y = 0.5f * zi[1] * (1.f + erff(zi[1] * 0.70710678118654752f)) * scale;
        o4.z = 0.5f * zi[2] * (1.f + erff(zi[2] * 0.70710678118654752f)) * scale;
        o4.w = 0.5f * zi[3] * (1.f + erff(zi[3] * 0.70710678118654752f)) * scale;
        *(float4*)(ot + d0) = o4;
    }
}

extern "C" void kernel_launch(void* const* d_in, const int* in_sizes, int n_in,
                              void* d_out, int out_size, void* d_ws, size_t ws_size,
                              hipStream_t stream)
{
    const float* x    = (const float*)d_in[0];
    const float* Wq   = (const float*)d_in[1];
    const float* Wk   = (const float*)d_in[2];
    const float* gain = (const float*)d_in[3];
    const float* bias = (const float*)d_in[4];
    const float* plm  = (const float*)d_in[5];
    const float* pls  = (const float*)d_in[6];
    float* out = (float*)d_out;

    float* ws      = (float*)d_ws;
    float* q       = ws;                       // 262144
    float* k       = ws + 262144;              // 262144
    float* meansum = ws + 524288;              // 2048
    float* pvals   = ws + 526336;              // B*T*CPR = 3145728
    int*   pidx    = (int*)(ws + 3672064);     // 3145728
    __bf16* xhi    = (__bf16*)(ws + 6817792);  // B*T*D bf16 (4194304 float-slots)
    __bf16* xlo    = xhi + (size_t)B * T * D;
    __bf16* Whi    = xlo + (size_t)B * T * D;  // 64*1024 bf16
    __bf16* Wlo    = Whi + 64 * D;
    float* selw    = ws + 15271936;            // B*T*8 = 65536
    int*   selg    = (int*)(ws + 15337472);    // 65536
    // total ws use: ~61.6 MB

    hipMemsetAsync(meansum, 0, 2048 * sizeof(float), stream);
    conv_kernel<<<B * T * D / 2048, 256, 0, stream>>>(x, xhi, xlo);
    conv_kernel<<<16, 256, 0, stream>>>(Wq, Whi, Wlo);
    conv_kernel<<<16, 256, 0, stream>>>(Wk, Whi + 32 * D, Wlo + 32 * D);
    mean_kernel<<<128, 256, 0, stream>>>(x, meansum);
    qk_mfma_kernel<<<B * T / 128, 256, 0, stream>>>(xhi, xlo, Whi, Wlo, q, k);
    topk_mfma_kernel<<<B * NBLK, 256, 0, stream>>>(xhi, pvals, pidx);
    select_kernel<<<B * T / 4, 256, 0, stream>>>(x, q, k, pvals, pidx, selw, selg);
    msg_kernel<<<B * T / 4, 256, 0, stream>>>(x, meansum, selw, selg,
                                              gain, bias, plm, pls, out);
}

// Round 11
// 400.768 us; speedup vs baseline: 1.1988x; 1.1988x over previous
//
#include <hip/hip_runtime.h>
#include <math.h>

#define B 2
#define T 4096
#define D 1024
#define DH 32
#define TNB 32        // 128-row tiles per batch
#define NBLK 528      // TNB*(TNB+1)/2 causal tile pairs
#define NK 12         // per-chunk candidates kept (safety margin over 8)
#define CPR (32*NK)   // candidates per row = 384

typedef __bf16 bf16x8 __attribute__((ext_vector_type(8)));
typedef float f32x4 __attribute__((ext_vector_type(4)));

// ---------------- K_conv: src -> (hi, lo) bf16 split (2048 elems/block) -------
__global__ __launch_bounds__(256) void conv_kernel(const float* __restrict__ x,
        __bf16* __restrict__ xhi, __bf16* __restrict__ xlo)
{
    int i = (blockIdx.x * 256 + threadIdx.x) << 3;     // 8 floats/thread
    float4 a = *(const float4*)(x + i);
    float4 c = *(const float4*)(x + i + 4);
    float av[8] = {a.x, a.y, a.z, a.w, c.x, c.y, c.z, c.w};
    __bf16 h[8], l[8];
    #pragma unroll
    for (int j = 0; j < 8; ++j) {
        h[j] = (__bf16)av[j];
        l[j] = (__bf16)(av[j] - (float)h[j]);
    }
    *(float4*)(xhi + i) = *(float4*)h;
    *(float4*)(xlo + i) = *(float4*)l;
}

// ---------------- K0: per-batch column sums (for the t=0 row) ----------------
__global__ void mean_kernel(const float* __restrict__ x, float* __restrict__ meansum)
{
    int gid  = blockIdx.x;           // B * 4 dblk * 16 tch = 128 blocks
    int b    = gid >> 6;
    int rem  = gid & 63;
    int dblk = rem >> 4;
    int tch  = rem & 15;
    int d = dblk * 256 + threadIdx.x;
    const float* xp = x + (b * T + tch * 256) * D + d;
    float s = 0.f;
    #pragma unroll 8
    for (int it = 0; it < 256; ++it) s += xp[it * D];
    atomicAdd(&meansum[(b << 10) + d], s);
}

// ---------------- K1: q/k projection as split-bf16 MFMA GEMM -----------------
__global__ __launch_bounds__(256) void qk_mfma_kernel(
        const __bf16* __restrict__ xhi, const __bf16* __restrict__ xlo,
        const __bf16* __restrict__ Whi, const __bf16* __restrict__ Wlo,
        float* __restrict__ qo, float* __restrict__ ko)
{
    __shared__ __align__(16) __bf16 stg[15360];
    __bf16* sAhi = stg;            // 128 x 40
    __bf16* sAlo = stg + 5120;
    __bf16* sBhi = stg + 10240;    // 64 x 40
    __bf16* sBlo = stg + 12800;

    int tid = threadIdx.x;
    int m0 = blockIdx.x << 7;
    int w = tid >> 6, lane = tid & 63;
    int fr = lane & 15, fq = lane >> 4;

    int arow = tid >> 1, ah = tid & 1;      // A staging: 2 chunks of 16 bf16
    int brow = tid >> 2, bq = tid & 3;      // B staging: 4 chunks of 8 bf16

    const __bf16* gAh = xhi + (size_t)(m0 + arow) * D + ah * 16;
    const __bf16* gAl = xlo + (size_t)(m0 + arow) * D + ah * 16;
    const __bf16* gBh = Whi + brow * D + bq * 8;
    const __bf16* gBl = Wlo + brow * D + bq * 8;

    f32x4 acc[2][4];
    #pragma unroll
    for (int i = 0; i < 2; ++i)
        #pragma unroll
        for (int j = 0; j < 4; ++j) acc[i][j] = (f32x4){0.f, 0.f, 0.f, 0.f};

    float4 a0 = *(const float4*)(gAh);
    float4 a1 = *(const float4*)(gAh + 8);
    float4 a2 = *(const float4*)(gAl);
    float4 a3 = *(const float4*)(gAl + 8);
    float4 b0 = *(const float4*)(gBh);
    float4 b1 = *(const float4*)(gBl);

    int sa = arow * 40 + ah * 16;
    int sb = brow * 40 + bq * 8;

    for (int kc = 0; kc < 32; ++kc) {
        __syncthreads();
        *(float4*)(sAhi + sa) = a0;  *(float4*)(sAhi + sa + 8) = a1;
        *(float4*)(sAlo + sa) = a2;  *(float4*)(sAlo + sa + 8) = a3;
        *(float4*)(sBhi + sb) = b0;  *(float4*)(sBlo + sb) = b1;
        __syncthreads();
        if (kc + 1 < 32) {
            int k0 = (kc + 1) << 5;
            a0 = *(const float4*)(gAh + k0);
            a1 = *(const float4*)(gAh + k0 + 8);
            a2 = *(const float4*)(gAl + k0);
            a3 = *(const float4*)(gAl + k0 + 8);
            b0 = *(const float4*)(gBh + k0);
            b1 = *(const float4*)(gBl + k0);
        }
        bf16x8 fah[2], fal[2], fbh[4], fbl[4];
        #pragma unroll
        for (int i = 0; i < 2; ++i) {
            int r = (w << 5) + i * 16 + fr;
            fah[i] = *(const bf16x8*)(sAhi + r * 40 + fq * 8);
            fal[i] = *(const bf16x8*)(sAlo + r * 40 + fq * 8);
        }
        #pragma unroll
        for (int j = 0; j < 4; ++j) {
            int r = j * 16 + fr;
            fbh[j] = *(const bf16x8*)(sBhi + r * 40 + fq * 8);
            fbl[j] = *(const bf16x8*)(sBlo + r * 40 + fq * 8);
        }
        #pragma unroll
        for (int i = 0; i < 2; ++i)
            #pragma unroll
            for (int j = 0; j < 4; ++j) {
                acc[i][j] = __builtin_amdgcn_mfma_f32_16x16x32_bf16(fah[i], fbh[j], acc[i][j], 0, 0, 0);
                acc[i][j] = __builtin_amdgcn_mfma_f32_16x16x32_bf16(fah[i], fbl[j], acc[i][j], 0, 0, 0);
                acc[i][j] = __builtin_amdgcn_mfma_f32_16x16x32_bf16(fal[i], fbh[j], acc[i][j], 0, 0, 0);
            }
    }
    // writeout: C layout col=lane&15, row=fq*4+reg
    #pragma unroll
    for (int i = 0; i < 2; ++i) {
        int grow0 = m0 + (w << 5) + i * 16 + (fq << 2);
        #pragma unroll
        for (int j = 0; j < 4; ++j) {
            int gn = j * 16 + fr;
            float* dst = (gn < 32) ? (qo + grow0 * DH + gn)
                                   : (ko + grow0 * DH + gn - 32);
            dst[0]      = acc[i][j][0];
            dst[DH]     = acc[i][j][1];
            dst[2 * DH] = acc[i][j][2];
            dst[3 * DH] = acc[i][j][3];
        }
    }
}

// ---------------- K2: hi-only bf16 MFMA sim GEMM + per-row top-12 per 128-col chunk
// (round-9 version, best measured: LDS-staged, prefetch after barrier 2,
//  two-phase 64x129 score buffer, 8-wide batched scan)
__global__ __launch_bounds__(256, 4) void topk_mfma_kernel(
        const __bf16* __restrict__ xhi,
        float* __restrict__ pvals, int* __restrict__ pidx)
{
    __shared__ __align__(16) float Sbuf[64 * 129];     // 33024 B, aliases staging
    __bf16* stg = (__bf16*)Sbuf;
    __bf16* sA = stg;                // 128 x 40 = 5120 bf16
    __bf16* sB = stg + 5120;         // 128 x 40

    int tid = threadIdx.x;
    int b = blockIdx.x / NBLK;
    int l = blockIdx.x - b * NBLK;
    int rt = (int)((sqrtf(8.f * l + 1.f) - 1.f) * 0.5f);
    while ((rt + 1) * (rt + 2) / 2 <= l) ++rt;
    while (rt * (rt + 1) / 2 > l) --rt;
    int ct = l - rt * (rt + 1) / 2;
    int r0 = rt << 7, c0 = ct << 7;
    int base = b * T;

    int w = tid >> 6, lane = tid & 63;
    int wr = (w >> 1) << 6, wc = (w & 1) << 6;
    bool active = !(rt == ct && w == 1);   // diag block, fully non-causal quadrant

    int srow = tid >> 2, sq = tid & 3;     // staging: thread -> (row, 16B chunk)
    int fr = lane & 15, fq = lane >> 4;    // fragment: row-in-tile, k-quad

    const __bf16* gA = xhi + (base + r0) * D;
    const __bf16* gB = xhi + (base + c0) * D;

    f32x4 acc[4][4];
    #pragma unroll
    for (int i = 0; i < 4; ++i)
        #pragma unroll
        for (int j = 0; j < 4; ++j) acc[i][j] = (f32x4){0.f, 0.f, 0.f, 0.f};

    int o0 = srow * D + sq * 8;
    int o1 = o0 + 64 * D;
    float4 pf0 = *(const float4*)(gA + o0);
    float4 pf1 = *(const float4*)(gA + o1);
    float4 pf4 = *(const float4*)(gB + o0);
    float4 pf5 = *(const float4*)(gB + o1);

    int s0 = srow * 40 + sq * 8;
    int s1 = s0 + 64 * 40;

    for (int kc = 0; kc < 32; ++kc) {
        __syncthreads();                   // drains loads issued last MFMA phase (cheap)
        *(float4*)(sA + s0) = pf0;  *(float4*)(sA + s1) = pf1;
        *(float4*)(sB + s0) = pf4;  *(float4*)(sB + s1) = pf5;
        __syncthreads();                   // no fresh vm ops outstanding here
        if (kc + 1 < 32) {                 // prefetch AFTER barrier: overlaps MFMA phase
            int k0 = (kc + 1) << 5;
            int n0 = srow * D + k0 + sq * 8;
            int n1 = n0 + 64 * D;
            pf0 = *(const float4*)(gA + n0);
            pf1 = *(const float4*)(gA + n1);
            pf4 = *(const float4*)(gB + n0);
            pf5 = *(const float4*)(gB + n1);
        }
        if (active) {
            bf16x8 ah[4], bh[4];
            #pragma unroll
            for (int i = 0; i < 4; ++i) {
                int ar = wr + i * 16 + fr;
                ah[i] = *(const bf16x8*)(sA + ar * 40 + fq * 8);
                int bc = wc + i * 16 + fr;
                bh[i] = *(const bf16x8*)(sB + bc * 40 + fq * 8);
            }
            #pragma unroll
            for (int i = 0; i < 4; ++i)
                #pragma unroll
                for (int j = 0; j < 4; ++j)
                    acc[i][j] = __builtin_amdgcn_mfma_f32_16x16x32_bf16(ah[i], bh[j], acc[i][j], 0, 0, 0);
        }
    }

    int cr = fq << 2, cc = fr;             // C layout: col=lane&15, row=fq*4+reg
    #pragma unroll
    for (int phase = 0; phase < 2; ++phase) {
        __syncthreads();                   // staging reads / prior scan done
        if ((w >> 1) == phase) {           // waves owning rows [phase*64, +64)
            #pragma unroll
            for (int i = 0; i < 4; ++i)
                #pragma unroll
                for (int j = 0; j < 4; ++j) {
                    float* sp = Sbuf + (i * 16 + cr) * 129 + wc + j * 16 + cc;
                    sp[0]       = acc[i][j][0];
                    sp[129]     = acc[i][j][1];
                    sp[2 * 129] = acc[i][j][2];
                    sp[3 * 129] = acc[i][j][3];
                }
        }
        __syncthreads();
        if (tid < 64) {                    // per-row top-12, 8-wide batched loads
            int gt = r0 + (phase << 6) + tid;
            int cmax = gt - c0;
            if (cmax > 128) cmax = 128;
            if (cmax < 0) cmax = 0;
            float tv[NK]; int ti[NK];
            #pragma unroll
            for (int i = 0; i < NK; ++i) { tv[i] = -INFINITY; ti[i] = -1; }
            float vmin = -INFINITY; int minp = 0;
            const float* Srow = Sbuf + tid * 129;
            for (int cb = 0; cb < cmax; cb += 8) {
                float v[8];
                #pragma unroll
                for (int j = 0; j < 8; ++j) v[j] = Srow[cb + j];   // 8 loads in flight
                #pragma unroll
                for (int j = 0; j < 8; ++j) {
                    int c = cb + j;
                    float vv = v[j];
                    if (c < cmax && vv > vmin) {
                        tv[minp] = vv; ti[minp] = c0 + c;
                        vmin = tv[0]; minp = 0;
                        #pragma unroll
                        for (int i = 1; i < NK; ++i)
                            if (tv[i] < vmin) { vmin = tv[i]; minp = i; }
                    }
                }
            }
            int ob = (base + gt) * CPR + ct * NK;
            #pragma unroll
            for (int i = 0; i < NK; ++i) { pvals[ob + i] = tv[i]; pidx[ob + i] = ti[i]; }
        }
    }
}

// ---------------- K3: FUSED wave-per-row selection + message + gelu ----------
// Same selection math as the passing select_kernel; after softmax the wave
// re-loads its 8 selected rows (L1/L2-hot from the re-rank) and accumulates
// msg per-lane over the identical dim mapping -> no second kernel, no L3
// re-gather, no selw/selg round trip. Bit-identical output.
__global__ __launch_bounds__(256) void select_msg_kernel(const float* __restrict__ x,
        const float* __restrict__ q, const float* __restrict__ k,
        const float* __restrict__ meansum,
        const float* __restrict__ pvals, const int* __restrict__ pidx,
        const float* __restrict__ gain, const float* __restrict__ bias,
        const float* __restrict__ plm, const float* __restrict__ pls,
        float* __restrict__ out)
{
    int tid = threadIdx.x;
    int w = tid >> 6, lane = tid & 63;
    int rid = (blockIdx.x << 2) + w;         // global row b*T+t
    int b = rid >> 12, t = rid & (T - 1);
    int ncand = NK * ((t + 127) >> 7);

    // candidate loads (all in flight)
    float cv[6]; int ci[6];
    #pragma unroll
    for (int u = 0; u < 6; ++u) {
        int cid = lane + (u << 6);
        bool val = cid < ncand;
        cv[u] = val ? pvals[(size_t)rid * CPR + cid] : -INFINITY;
        ci[u] = val ? pidx[(size_t)rid * CPR + cid] : -1;
    }
    // prefetch xt fragments (independent of merge)
    const float* xt = x + (size_t)rid * D;
    float4 xt4[4];
    #pragma unroll
    for (int c = 0; c < 4; ++c)
        xt4[c] = *(const float4*)(xt + (c << 8) + (lane << 2));

    // butterfly merge -> approx top-12 (identical logic/tie-breaks)
    float sv[NK]; int si[NK];
    #pragma unroll
    for (int i = 0; i < NK; ++i) {
        float mv = cv[0]; int mi = ci[0];
        #pragma unroll
        for (int u = 1; u < 6; ++u)
            if (cv[u] > mv || (cv[u] == mv && ci[u] < mi)) { mv = cv[u]; mi = ci[u]; }
        #pragma unroll
        for (int off = 32; off >= 1; off >>= 1) {
            float ov = __shfl_xor(mv, off);
            int   oi = __shfl_xor(mi, off);
            if (ov > mv || (ov == mv && oi < mi)) { mv = ov; mi = oi; }
        }
        sv[i] = mv; si[i] = mi;
        #pragma unroll
        for (int u = 0; u < 6; ++u)
            if (cv[u] == mv && ci[u] == mi) cv[u] = -INFINITY;
    }

    // exact fp32 re-rank: 4 batches of 3 candidates, loads batched in flight
    float ex[NK];
    #pragma unroll
    for (int batch = 0; batch < 4; ++batch) {
        float4 rv[3][4];
        #pragma unroll
        for (int s = 0; s < 3; ++s) {
            int i = batch * 3 + s;
            int sj = si[i];
            const float* xj = x + (size_t)((b << 12) + (sj >= 0 ? sj : 0)) * D;
            #pragma unroll
            for (int c = 0; c < 4; ++c)
                rv[s][c] = *(const float4*)(xj + (c << 8) + (lane << 2));
        }
        #pragma unroll
        for (int s = 0; s < 3; ++s) {
            float ss = 0.f;
            #pragma unroll
            for (int c = 0; c < 4; ++c)
                ss += xt4[c].x * rv[s][c].x + xt4[c].y * rv[s][c].y
                    + xt4[c].z * rv[s][c].z + xt4[c].w * rv[s][c].w;
            ex[batch * 3 + s] = ss;
        }
    }
    // shuffle-reduce all 12 (independent chains pipeline)
    #pragma unroll
    for (int i = 0; i < NK; ++i) {
        float ssum = ex[i];
        #pragma unroll
        for (int off = 32; off >= 1; off >>= 1) ssum += __shfl_xor(ssum, off);
        ex[i] = (si[i] >= 0) ? ssum : -INFINITY;
    }

    // exact top-8 (tie-break: lower index) — every lane computes identically
    float bv[8]; int bi[8];
    #pragma unroll
    for (int r = 0; r < 8; ++r) {
        int mp = 0;
        #pragma unroll
        for (int i = 1; i < NK; ++i) {
            bool better = (ex[i] > ex[mp]) ||
                          (ex[i] == ex[mp] && si[i] >= 0 &&
                           (si[mp] < 0 || si[i] < si[mp]));
            if (better) mp = i;
        }
        bv[r] = ex[mp]; bi[r] = si[mp];
        ex[mp] = -INFINITY;
    }

    // scores: lanes 8i..8i+7 compute dot(q[t], k[sel_i])
    int i8 = lane >> 3, e = lane & 7;
    bool v8 = bv[i8] > -1e37f;
    int g8 = v8 ? bi[i8] : 0;
    float4 qv = *(const float4*)(q + (size_t)rid * DH + (e << 2));
    float4 kv = *(const float4*)(k + (size_t)((b << 12) + g8) * DH + (e << 2));
    float p = qv.x * kv.x + qv.y * kv.y + qv.z * kv.z + qv.w * kv.w;
    p += __shfl_xor(p, 1); p += __shfl_xor(p, 2); p += __shfl_xor(p, 4);
    p *= 0.17677669529663687f;               // 1/sqrt(32)

    float sc[8];
    #pragma unroll
    for (int i = 0; i < 8; ++i) sc[i] = __shfl(p, i << 3);

    float m = -INFINITY; int cnt = 0;
    #pragma unroll
    for (int i = 0; i < 8; ++i)
        if (bv[i] > -1e37f) { ++cnt; if (sc[i] > m) m = sc[i]; }

    float wgt[8]; float Z = 0.f; int gsel[8];
    #pragma unroll
    for (int i = 0; i < 8; ++i) {
        bool val = bv[i] > -1e37f;
        wgt[i] = val ? expf(sc[i] - m) : 0.f;
        Z += wgt[i];
        gsel[i] = val ? ((b << 12) + bi[i]) : (b << 12);
    }
    float invZ = (cnt > 0) ? 1.f / Z : 0.f;
    #pragma unroll
    for (int i = 0; i < 8; ++i) wgt[i] *= invZ;

    // ---- fused epilogue: msg accumulation on lane's 16 dims + gelu ----
    float mix   = 1.f / (1.f + expf(-plm[0]));
    float scale = log1pf(expf(pls[0])) + 0.01f;
    const float onemix = 1.f - mix;

    float4 msg4[4];
    if (cnt == 0) {                          // t==0: uniform attention over ALL T
        #pragma unroll
        for (int c = 0; c < 4; ++c) {
            float4 ms = *(const float4*)(meansum + (b << 10) + (c << 8) + (lane << 2));
            msg4[c].x = ms.x * (1.f / (float)T); msg4[c].y = ms.y * (1.f / (float)T);
            msg4[c].z = ms.z * (1.f / (float)T); msg4[c].w = ms.w * (1.f / (float)T);
        }
    } else {
        #pragma unroll
        for (int c = 0; c < 4; ++c) msg4[c] = (float4){0.f, 0.f, 0.f, 0.f};
        #pragma unroll
        for (int g = 0; g < 2; ++g) {        // 2 batches of 4 rows (L2-hot re-read)
            float4 rv[4][4];
            #pragma unroll
            for (int s = 0; s < 4; ++s) {
                const float* xj = x + (size_t)gsel[g * 4 + s] * D;
                #pragma unroll
                for (int c = 0; c < 4; ++c)
                    rv[s][c] = *(const float4*)(xj + (c << 8) + (lane << 2));
            }
            #pragma unroll
            for (int s = 0; s < 4; ++s) {    // preserves i=0..7 summation order
                float wi = wgt[g * 4 + s];
                #pragma unroll
                for (int c = 0; c < 4; ++c) {
                    msg4[c].x += wi * rv[s][c].x; msg4[c].y += wi * rv[s][c].y;
                    msg4[c].z += wi * rv[s][c].z; msg4[c].w += wi * rv[s][c].w;
                }
            }
        }
    }
    #pragma unroll
    for (int c = 0; c < 4; ++c) {
        int d0 = (c << 8) + (lane << 2);
        float4 g4 = *(const float4*)(gain + d0);
        float4 b4 = *(const float4*)(bias + d0);
        float4 xv = xt4[c];
        float zi[4] = {
            (mix * xv.x + onemix * msg4[c].x) * g4.x + b4.x,
            (mix * xv.y + onemix * msg4[c].y) * g4.y + b4.y,
            (mix * xv.z + onemix * msg4[c].z) * g4.z + b4.z,
            (mix * xv.w + onemix * msg4[c].w) * g4.w + b4.w };
        float4 o4;
        o4.x = 0.5f * zi[0] * (1.f + erff(zi[0] * 0.70710678118654752f)) * scale;
        o4.y = 0.5f * zi[1] * (1.f + erff(zi[1] * 0.70710678118654752f)) * scale;
        o4.z = 0.5f * zi[2] * (1.f + erff(zi[2] * 0.70710678118654752f)) * scale;
        o4.w = 0.5f * zi[3] * (1.f + erff(zi[3] * 0.70710678118654752f)) * scale;
        *(float4*)(out + (size_t)rid * D + d0) = o4;
    }
}

extern "C" void kernel_launch(void* const* d_in, const int* in_sizes, int n_in,
                              void* d_out, int out_size, void* d_ws, size_t ws_size,
                              hipStream_t stream)
{
    const float* x    = (const float*)d_in[0];
    const float* Wq   = (const float*)d_in[1];
    const float* Wk   = (const float*)d_in[2];
    const float* gain = (const float*)d_in[3];
    const float* bias = (const float*)d_in[4];
    const float* plm  = (const float*)d_in[5];
    const float* pls  = (const float*)d_in[6];
    float* out = (float*)d_out;

    float* ws      = (float*)d_ws;
    float* q       = ws;                       // 262144
    float* k       = ws + 262144;              // 262144
    float* meansum = ws + 524288;              // 2048
    float* pvals   = ws + 526336;              // B*T*CPR = 3145728
    int*   pidx    = (int*)(ws + 3672064);     // 3145728
    __bf16* xhi    = (__bf16*)(ws + 6817792);  // B*T*D bf16 (4194304 float-slots)
    __bf16* xlo    = xhi + (size_t)B * T * D;
    __bf16* Whi    = xlo + (size_t)B * T * D;  // 64*1024 bf16
    __bf16* Wlo    = Whi + 64 * D;
    // total ws use: ~61 MB

    hipMemsetAsync(meansum, 0, 2048 * sizeof(float), stream);
    conv_kernel<<<B * T * D / 2048, 256, 0, stream>>>(x, xhi, xlo);
    conv_kernel<<<16, 256, 0, stream>>>(Wq, Whi, Wlo);
    conv_kernel<<<16, 256, 0, stream>>>(Wk, Whi + 32 * D, Wlo + 32 * D);
    mean_kernel<<<128, 256, 0, stream>>>(x, meansum);
    qk_mfma_kernel<<<B * T / 128, 256, 0, stream>>>(xhi, xlo, Whi, Wlo, q, k);
    topk_mfma_kernel<<<B * NBLK, 256, 0, stream>>>(xhi, pvals, pidx);
    select_msg_kernel<<<B * T / 4, 256, 0, stream>>>(x, q, k, meansum, pvals, pidx,
                                                     gain, bias, plm, pls, out);
}

// Round 12
// 393.601 us; speedup vs baseline: 1.2206x; 1.0182x over previous
//
#include <hip/hip_runtime.h>
#include <math.h>

#define B 2
#define T 4096
#define D 1024
#define DH 32
#define TNB 32        // 128-row tiles per batch
#define NBLK 528      // TNB*(TNB+1)/2 causal tile pairs
#define NK 12         // per-chunk candidates kept (safety margin over 8)
#define CPR (32*NK)   // candidates per row = 384

typedef __bf16 bf16x8 __attribute__((ext_vector_type(8)));
typedef float f32x4 __attribute__((ext_vector_type(4)));

#define AS1 __attribute__((address_space(1)))
#define AS3 __attribute__((address_space(3)))

// ---------------- K_conv: src -> (hi, lo) bf16 split (2048 elems/block) -------
__global__ __launch_bounds__(256) void conv_kernel(const float* __restrict__ x,
        __bf16* __restrict__ xhi, __bf16* __restrict__ xlo)
{
    int i = (blockIdx.x * 256 + threadIdx.x) << 3;     // 8 floats/thread
    float4 a = *(const float4*)(x + i);
    float4 c = *(const float4*)(x + i + 4);
    float av[8] = {a.x, a.y, a.z, a.w, c.x, c.y, c.z, c.w};
    __bf16 h[8], l[8];
    #pragma unroll
    for (int j = 0; j < 8; ++j) {
        h[j] = (__bf16)av[j];
        l[j] = (__bf16)(av[j] - (float)h[j]);
    }
    *(float4*)(xhi + i) = *(float4*)h;
    *(float4*)(xlo + i) = *(float4*)l;
}

// ---------------- K0: per-batch column sums (for the t=0 row) ----------------
__global__ void mean_kernel(const float* __restrict__ x, float* __restrict__ meansum)
{
    int gid  = blockIdx.x;           // B * 4 dblk * 16 tch = 128 blocks
    int b    = gid >> 6;
    int rem  = gid & 63;
    int dblk = rem >> 4;
    int tch  = rem & 15;
    int d = dblk * 256 + threadIdx.x;
    const float* xp = x + (b * T + tch * 256) * D + d;
    float s = 0.f;
    #pragma unroll 8
    for (int it = 0; it < 256; ++it) s += xp[it * D];
    atomicAdd(&meansum[(b << 10) + d], s);
}

// ---------------- K1: q/k projection as split-bf16 MFMA GEMM -----------------
__global__ __launch_bounds__(256) void qk_mfma_kernel(
        const __bf16* __restrict__ xhi, const __bf16* __restrict__ xlo,
        const __bf16* __restrict__ Whi, const __bf16* __restrict__ Wlo,
        float* __restrict__ qo, float* __restrict__ ko)
{
    __shared__ __align__(16) __bf16 stg[15360];
    __bf16* sAhi = stg;            // 128 x 40
    __bf16* sAlo = stg + 5120;
    __bf16* sBhi = stg + 10240;    // 64 x 40
    __bf16* sBlo = stg + 12800;

    int tid = threadIdx.x;
    int m0 = blockIdx.x << 7;
    int w = tid >> 6, lane = tid & 63;
    int fr = lane & 15, fq = lane >> 4;

    int arow = tid >> 1, ah = tid & 1;      // A staging: 2 chunks of 16 bf16
    int brow = tid >> 2, bq = tid & 3;      // B staging: 4 chunks of 8 bf16

    const __bf16* gAh = xhi + (size_t)(m0 + arow) * D + ah * 16;
    const __bf16* gAl = xlo + (size_t)(m0 + arow) * D + ah * 16;
    const __bf16* gBh = Whi + brow * D + bq * 8;
    const __bf16* gBl = Wlo + brow * D + bq * 8;

    f32x4 acc[2][4];
    #pragma unroll
    for (int i = 0; i < 2; ++i)
        #pragma unroll
        for (int j = 0; j < 4; ++j) acc[i][j] = (f32x4){0.f, 0.f, 0.f, 0.f};

    float4 a0 = *(const float4*)(gAh);
    float4 a1 = *(const float4*)(gAh + 8);
    float4 a2 = *(const float4*)(gAl);
    float4 a3 = *(const float4*)(gAl + 8);
    float4 b0 = *(const float4*)(gBh);
    float4 b1 = *(const float4*)(gBl);

    int sa = arow * 40 + ah * 16;
    int sb = brow * 40 + bq * 8;

    for (int kc = 0; kc < 32; ++kc) {
        __syncthreads();
        *(float4*)(sAhi + sa) = a0;  *(float4*)(sAhi + sa + 8) = a1;
        *(float4*)(sAlo + sa) = a2;  *(float4*)(sAlo + sa + 8) = a3;
        *(float4*)(sBhi + sb) = b0;  *(float4*)(sBlo + sb) = b1;
        __syncthreads();
        if (kc + 1 < 32) {
            int k0 = (kc + 1) << 5;
            a0 = *(const float4*)(gAh + k0);
            a1 = *(const float4*)(gAh + k0 + 8);
            a2 = *(const float4*)(gAl + k0);
            a3 = *(const float4*)(gAl + k0 + 8);
            b0 = *(const float4*)(gBh + k0);
            b1 = *(const float4*)(gBl + k0);
        }
        bf16x8 fah[2], fal[2], fbh[4], fbl[4];
        #pragma unroll
        for (int i = 0; i < 2; ++i) {
            int r = (w << 5) + i * 16 + fr;
            fah[i] = *(const bf16x8*)(sAhi + r * 40 + fq * 8);
            fal[i] = *(const bf16x8*)(sAlo + r * 40 + fq * 8);
        }
        #pragma unroll
        for (int j = 0; j < 4; ++j) {
            int r = j * 16 + fr;
            fbh[j] = *(const bf16x8*)(sBhi + r * 40 + fq * 8);
            fbl[j] = *(const bf16x8*)(sBlo + r * 40 + fq * 8);
        }
        #pragma unroll
        for (int i = 0; i < 2; ++i)
            #pragma unroll
            for (int j = 0; j < 4; ++j) {
                acc[i][j] = __builtin_amdgcn_mfma_f32_16x16x32_bf16(fah[i], fbh[j], acc[i][j], 0, 0, 0);
                acc[i][j] = __builtin_amdgcn_mfma_f32_16x16x32_bf16(fah[i], fbl[j], acc[i][j], 0, 0, 0);
                acc[i][j] = __builtin_amdgcn_mfma_f32_16x16x32_bf16(fal[i], fbh[j], acc[i][j], 0, 0, 0);
            }
    }
    // writeout: C layout col=lane&15, row=fq*4+reg
    #pragma unroll
    for (int i = 0; i < 2; ++i) {
        int grow0 = m0 + (w << 5) + i * 16 + (fq << 2);
        #pragma unroll
        for (int j = 0; j < 4; ++j) {
            int gn = j * 16 + fr;
            float* dst = (gn < 32) ? (qo + grow0 * DH + gn)
                                   : (ko + grow0 * DH + gn - 32);
            dst[0]      = acc[i][j][0];
            dst[DH]     = acc[i][j][1];
            dst[2 * DH] = acc[i][j][2];
            dst[3 * DH] = acc[i][j][3];
        }
    }
}

// ---------------- K2: hi-only bf16 MFMA sim GEMM + per-row top-12 per 128-col chunk
// Async double-buffered staging via global_load_lds (16 B/lane, wave-uniform
// base + lane*16: unpadded 64 B rows give LDS offset == lane*16 exactly).
// One barrier per K-iter; loads for tile k+1 fly during tile k's MFMA phase.
__global__ __launch_bounds__(256, 4) void topk_mfma_kernel(
        const __bf16* __restrict__ xhi,
        float* __restrict__ pvals, int* __restrict__ pidx)
{
    __shared__ __align__(16) float Sbuf[64 * 129];     // 33024 B; staging aliases
    __bf16* stg = (__bf16*)Sbuf;
    // buf layout (bf16 units): A0 @0 (4096), B0 @4096, A1 @8192, B1 @12288

    int tid = threadIdx.x;
    int b = blockIdx.x / NBLK;
    int l = blockIdx.x - b * NBLK;
    int rt = (int)((sqrtf(8.f * l + 1.f) - 1.f) * 0.5f);
    while ((rt + 1) * (rt + 2) / 2 <= l) ++rt;
    while (rt * (rt + 1) / 2 > l) --rt;
    int ct = l - rt * (rt + 1) / 2;
    int r0 = rt << 7, c0 = ct << 7;
    int base = b * T;

    int w = tid >> 6, lane = tid & 63;
    int wr = (w >> 1) << 6, wc = (w & 1) << 6;
    bool active = !(rt == ct && w == 1);   // diag block, fully non-causal quadrant
    int fr = lane & 15, fq = lane >> 4;    // fragment: row-in-tile, k-quad

    // staging: lane i of wave w covers (row 16w + (i>>2), 16B-chunk i&3)
    int lrow = lane >> 2, lcq = (lane & 3) << 3;       // bf16 offsets
    const __bf16* gA = xhi + (size_t)(base + r0) * D;
    const __bf16* gB = xhi + (size_t)(base + c0) * D;
    // per-lane global row offsets (A/B, halves 0/1)
    const __bf16* gA0 = gA + (size_t)((w << 4) + lrow) * D + lcq;
    const __bf16* gA1 = gA0 + (size_t)64 * D;
    const __bf16* gB0 = gB + (size_t)((w << 4) + lrow) * D + lcq;
    const __bf16* gB1 = gB0 + (size_t)64 * D;

    f32x4 acc[4][4];
    #pragma unroll
    for (int i = 0; i < 4; ++i)
        #pragma unroll
        for (int j = 0; j < 4; ++j) acc[i][j] = (f32x4){0.f, 0.f, 0.f, 0.f};

    // issue tile 0 into buf0
    {
        __bf16* bA = stg;           // buf0
        __bf16* bB = stg + 4096;
        __builtin_amdgcn_global_load_lds((const AS1 unsigned int*)(gA0),
            (AS3 unsigned int*)(bA + (w << 9)), 16, 0, 0);
        __builtin_amdgcn_global_load_lds((const AS1 unsigned int*)(gA1),
            (AS3 unsigned int*)(bA + 2048 + (w << 9)), 16, 0, 0);
        __builtin_amdgcn_global_load_lds((const AS1 unsigned int*)(gB0),
            (AS3 unsigned int*)(bB + (w << 9)), 16, 0, 0);
        __builtin_amdgcn_global_load_lds((const AS1 unsigned int*)(gB1),
            (AS3 unsigned int*)(bB + 2048 + (w << 9)), 16, 0, 0);
    }

    for (int kc = 0; kc < 32; ++kc) {
        __syncthreads();                   // tile kc resident in buf[kc&1]
        if (kc + 1 < 32) {                 // DMA tile kc+1 into the other buffer
            int ko = (kc + 1) << 5;
            __bf16* bA = stg + (((kc + 1) & 1) << 13);
            __bf16* bB = bA + 4096;
            __builtin_amdgcn_global_load_lds((const AS1 unsigned int*)(gA0 + ko),
                (AS3 unsigned int*)(bA + (w << 9)), 16, 0, 0);
            __builtin_amdgcn_global_load_lds((const AS1 unsigned int*)(gA1 + ko),
                (AS3 unsigned int*)(bA + 2048 + (w << 9)), 16, 0, 0);
            __builtin_amdgcn_global_load_lds((const AS1 unsigned int*)(gB0 + ko),
                (AS3 unsigned int*)(bB + (w << 9)), 16, 0, 0);
            __builtin_amdgcn_global_load_lds((const AS1 unsigned int*)(gB1 + ko),
                (AS3 unsigned int*)(bB + 2048 + (w << 9)), 16, 0, 0);
        }
        if (active) {
            const __bf16* cA = stg + ((kc & 1) << 13);
            const __bf16* cB = cA + 4096;
            bf16x8 ah[4], bh[4];
            #pragma unroll
            for (int i = 0; i < 4; ++i) {
                int ar = wr + i * 16 + fr;
                ah[i] = *(const bf16x8*)(cA + ar * 32 + fq * 8);
                int bc = wc + i * 16 + fr;
                bh[i] = *(const bf16x8*)(cB + bc * 32 + fq * 8);
            }
            #pragma unroll
            for (int i = 0; i < 4; ++i)
                #pragma unroll
                for (int j = 0; j < 4; ++j)
                    acc[i][j] = __builtin_amdgcn_mfma_f32_16x16x32_bf16(ah[i], bh[j], acc[i][j], 0, 0, 0);
        }
    }

    int cr = fq << 2, cc = fr;             // C layout: col=lane&15, row=fq*4+reg
    #pragma unroll
    for (int phase = 0; phase < 2; ++phase) {
        __syncthreads();                   // staging reads / prior scan done
        if ((w >> 1) == phase) {           // waves owning rows [phase*64, +64)
            #pragma unroll
            for (int i = 0; i < 4; ++i)
                #pragma unroll
                for (int j = 0; j < 4; ++j) {
                    float* sp = Sbuf + (i * 16 + cr) * 129 + wc + j * 16 + cc;
                    sp[0]       = acc[i][j][0];
                    sp[129]     = acc[i][j][1];
                    sp[2 * 129] = acc[i][j][2];
                    sp[3 * 129] = acc[i][j][3];
                }
        }
        __syncthreads();
        if (tid < 64) {                    // per-row top-12, 8-wide batched loads
            int gt = r0 + (phase << 6) + tid;
            int cmax = gt - c0;
            if (cmax > 128) cmax = 128;
            if (cmax < 0) cmax = 0;
            float tv[NK]; int ti[NK];
            #pragma unroll
            for (int i = 0; i < NK; ++i) { tv[i] = -INFINITY; ti[i] = -1; }
            float vmin = -INFINITY; int minp = 0;
            const float* Srow = Sbuf + tid * 129;
            for (int cb = 0; cb < cmax; cb += 8) {
                float v[8];
                #pragma unroll
                for (int j = 0; j < 8; ++j) v[j] = Srow[cb + j];   // 8 loads in flight
                #pragma unroll
                for (int j = 0; j < 8; ++j) {
                    int c = cb + j;
                    float vv = v[j];
                    if (c < cmax && vv > vmin) {
                        tv[minp] = vv; ti[minp] = c0 + c;
                        vmin = tv[0]; minp = 0;
                        #pragma unroll
                        for (int i = 1; i < NK; ++i)
                            if (tv[i] < vmin) { vmin = tv[i]; minp = i; }
                    }
                }
            }
            int ob = (base + gt) * CPR + ct * NK;
            #pragma unroll
            for (int i = 0; i < NK; ++i) { pvals[ob + i] = tv[i]; pidx[ob + i] = ti[i]; }
        }
    }
}

// ---------------- K3: FUSED wave-per-row selection + message + gelu ----------
__global__ __launch_bounds__(256) void select_msg_kernel(const float* __restrict__ x,
        const float* __restrict__ q, const float* __restrict__ k,
        const float* __restrict__ meansum,
        const float* __restrict__ pvals, const int* __restrict__ pidx,
        const float* __restrict__ gain, const float* __restrict__ bias,
        const float* __restrict__ plm, const float* __restrict__ pls,
        float* __restrict__ out)
{
    int tid = threadIdx.x;
    int w = tid >> 6, lane = tid & 63;
    int rid = (blockIdx.x << 2) + w;         // global row b*T+t
    int b = rid >> 12, t = rid & (T - 1);
    int ncand = NK * ((t + 127) >> 7);

    // candidate loads (all in flight)
    float cv[6]; int ci[6];
    #pragma unroll
    for (int u = 0; u < 6; ++u) {
        int cid = lane + (u << 6);
        bool val = cid < ncand;
        cv[u] = val ? pvals[(size_t)rid * CPR + cid] : -INFINITY;
        ci[u] = val ? pidx[(size_t)rid * CPR + cid] : -1;
    }
    // prefetch xt fragments (independent of merge)
    const float* xt = x + (size_t)rid * D;
    float4 xt4[4];
    #pragma unroll
    for (int c = 0; c < 4; ++c)
        xt4[c] = *(const float4*)(xt + (c << 8) + (lane << 2));

    // butterfly merge -> approx top-12 (identical logic/tie-breaks)
    float sv[NK]; int si[NK];
    #pragma unroll
    for (int i = 0; i < NK; ++i) {
        float mv = cv[0]; int mi = ci[0];
        #pragma unroll
        for (int u = 1; u < 6; ++u)
            if (cv[u] > mv || (cv[u] == mv && ci[u] < mi)) { mv = cv[u]; mi = ci[u]; }
        #pragma unroll
        for (int off = 32; off >= 1; off >>= 1) {
            float ov = __shfl_xor(mv, off);
            int   oi = __shfl_xor(mi, off);
            if (ov > mv || (ov == mv && oi < mi)) { mv = ov; mi = oi; }
        }
        sv[i] = mv; si[i] = mi;
        #pragma unroll
        for (int u = 0; u < 6; ++u)
            if (cv[u] == mv && ci[u] == mi) cv[u] = -INFINITY;
    }

    // exact fp32 re-rank: 4 batches of 3 candidates, loads batched in flight
    float ex[NK];
    #pragma unroll
    for (int batch = 0; batch < 4; ++batch) {
        float4 rv[3][4];
        #pragma unroll
        for (int s = 0; s < 3; ++s) {
            int i = batch * 3 + s;
            int sj = si[i];
            const float* xj = x + (size_t)((b << 12) + (sj >= 0 ? sj : 0)) * D;
            #pragma unroll
            for (int c = 0; c < 4; ++c)
                rv[s][c] = *(const float4*)(xj + (c << 8) + (lane << 2));
        }
        #pragma unroll
        for (int s = 0; s < 3; ++s) {
            float ss = 0.f;
            #pragma unroll
            for (int c = 0; c < 4; ++c)
                ss += xt4[c].x * rv[s][c].x + xt4[c].y * rv[s][c].y
                    + xt4[c].z * rv[s][c].z + xt4[c].w * rv[s][c].w;
            ex[batch * 3 + s] = ss;
        }
    }
    // shuffle-reduce all 12 (independent chains pipeline)
    #pragma unroll
    for (int i = 0; i < NK; ++i) {
        float ssum = ex[i];
        #pragma unroll
        for (int off = 32; off >= 1; off >>= 1) ssum += __shfl_xor(ssum, off);
        ex[i] = (si[i] >= 0) ? ssum : -INFINITY;
    }

    // exact top-8 (tie-break: lower index) — every lane computes identically
    float bv[8]; int bi[8];
    #pragma unroll
    for (int r = 0; r < 8; ++r) {
        int mp = 0;
        #pragma unroll
        for (int i = 1; i < NK; ++i) {
            bool better = (ex[i] > ex[mp]) ||
                          (ex[i] == ex[mp] && si[i] >= 0 &&
                           (si[mp] < 0 || si[i] < si[mp]));
            if (better) mp = i;
        }
        bv[r] = ex[mp]; bi[r] = si[mp];
        ex[mp] = -INFINITY;
    }

    // scores: lanes 8i..8i+7 compute dot(q[t], k[sel_i])
    int i8 = lane >> 3, e = lane & 7;
    bool v8 = bv[i8] > -1e37f;
    int g8 = v8 ? bi[i8] : 0;
    float4 qv = *(const float4*)(q + (size_t)rid * DH + (e << 2));
    float4 kv = *(const float4*)(k + (size_t)((b << 12) + g8) * DH + (e << 2));
    float p = qv.x * kv.x + qv.y * kv.y + qv.z * kv.z + qv.w * kv.w;
    p += __shfl_xor(p, 1); p += __shfl_xor(p, 2); p += __shfl_xor(p, 4);
    p *= 0.17677669529663687f;               // 1/sqrt(32)

    float sc[8];
    #pragma unroll
    for (int i = 0; i < 8; ++i) sc[i] = __shfl(p, i << 3);

    float m = -INFINITY; int cnt = 0;
    #pragma unroll
    for (int i = 0; i < 8; ++i)
        if (bv[i] > -1e37f) { ++cnt; if (sc[i] > m) m = sc[i]; }

    float wgt[8]; float Z = 0.f; int gsel[8];
    #pragma unroll
    for (int i = 0; i < 8; ++i) {
        bool val = bv[i] > -1e37f;
        wgt[i] = val ? expf(sc[i] - m) : 0.f;
        Z += wgt[i];
        gsel[i] = val ? ((b << 12) + bi[i]) : (b << 12);
    }
    float invZ = (cnt > 0) ? 1.f / Z : 0.f;
    #pragma unroll
    for (int i = 0; i < 8; ++i) wgt[i] *= invZ;

    // ---- fused epilogue: msg accumulation on lane's 16 dims + gelu ----
    float mix   = 1.f / (1.f + expf(-plm[0]));
    float scale = log1pf(expf(pls[0])) + 0.01f;
    const float onemix = 1.f - mix;

    float4 msg4[4];
    if (cnt == 0) {                          // t==0: uniform attention over ALL T
        #pragma unroll
        for (int c = 0; c < 4; ++c) {
            float4 ms = *(const float4*)(meansum + (b << 10) + (c << 8) + (lane << 2));
            msg4[c].x = ms.x * (1.f / (float)T); msg4[c].y = ms.y * (1.f / (float)T);
            msg4[c].z = ms.z * (1.f / (float)T); msg4[c].w = ms.w * (1.f / (float)T);
        }
    } else {
        #pragma unroll
        for (int c = 0; c < 4; ++c) msg4[c] = (float4){0.f, 0.f, 0.f, 0.f};
        #pragma unroll
        for (int g = 0; g < 2; ++g) {        // 2 batches of 4 rows (L2-hot re-read)
            float4 rv[4][4];
            #pragma unroll
            for (int s = 0; s < 4; ++s) {
                const float* xj = x + (size_t)gsel[g * 4 + s] * D;
                #pragma unroll
                for (int c = 0; c < 4; ++c)
                    rv[s][c] = *(const float4*)(xj + (c << 8) + (lane << 2));
            }
            #pragma unroll
            for (int s = 0; s < 4; ++s) {    // preserves i=0..7 summation order
                float wi = wgt[g * 4 + s];
                #pragma unroll
                for (int c = 0; c < 4; ++c) {
                    msg4[c].x += wi * rv[s][c].x; msg4[c].y += wi * rv[s][c].y;
                    msg4[c].z += wi * rv[s][c].z; msg4[c].w += wi * rv[s][c].w;
                }
            }
        }
    }
    #pragma unroll
    for (int c = 0; c < 4; ++c) {
        int d0 = (c << 8) + (lane << 2);
        float4 g4 = *(const float4*)(gain + d0);
        float4 b4 = *(const float4*)(bias + d0);
        float4 xv = xt4[c];
        float zi[4] = {
            (mix * xv.x + onemix * msg4[c].x) * g4.x + b4.x,
            (mix * xv.y + onemix * msg4[c].y) * g4.y + b4.y,
            (mix * xv.z + onemix * msg4[c].z) * g4.z + b4.z,
            (mix * xv.w + onemix * msg4[c].w) * g4.w + b4.w };
        float4 o4;
        o4.x = 0.5f * zi[0] * (1.f + erff(zi[0] * 0.70710678118654752f)) * scale;
        o4.y = 0.5f * zi[1] * (1.f + erff(zi[1] * 0.70710678118654752f)) * scale;
        o4.z = 0.5f * zi[2] * (1.f + erff(zi[2] * 0.70710678118654752f)) * scale;
        o4.w = 0.5f * zi[3] * (1.f + erff(zi[3] * 0.70710678118654752f)) * scale;
        *(float4*)(out + (size_t)rid * D + d0) = o4;
    }
}

extern "C" void kernel_launch(void* const* d_in, const int* in_sizes, int n_in,
                              void* d_out, int out_size, void* d_ws, size_t ws_size,
                              hipStream_t stream)
{
    const float* x    = (const float*)d_in[0];
    const float* Wq   = (const float*)d_in[1];
    const float* Wk   = (const float*)d_in[2];
    const float* gain = (const float*)d_in[3];
    const float* bias = (const float*)d_in[4];
    const float* plm  = (const float*)d_in[5];
    const float* pls  = (const float*)d_in[6];
    float* out = (float*)d_out;

    float* ws      = (float*)d_ws;
    float* q       = ws;                       // 262144
    float* k       = ws + 262144;              // 262144
    float* meansum = ws + 524288;              // 2048
    float* pvals   = ws + 526336;              // B*T*CPR = 3145728
    int*   pidx    = (int*)(ws + 3672064);     // 3145728
    __bf16* xhi    = (__bf16*)(ws + 6817792);  // B*T*D bf16 (4194304 float-slots)
    __bf16* xlo    = xhi + (size_t)B * T * D;
    __bf16* Whi    = xlo + (size_t)B * T * D;  // 64*1024 bf16
    __bf16* Wlo    = Whi + 64 * D;
    // total ws use: ~61 MB

    hipMemsetAsync(meansum, 0, 2048 * sizeof(float), stream);
    conv_kernel<<<B * T * D / 2048, 256, 0, stream>>>(x, xhi, xlo);
    conv_kernel<<<16, 256, 0, stream>>>(Wq, Whi, Wlo);
    conv_kernel<<<16, 256, 0, stream>>>(Wk, Whi + 32 * D, Wlo + 32 * D);
    mean_kernel<<<128, 256, 0, stream>>>(x, meansum);
    qk_mfma_kernel<<<B * T / 128, 256, 0, stream>>>(xhi, xlo, Whi, Wlo, q, k);
    topk_mfma_kernel<<<B * NBLK, 256, 0, stream>>>(xhi, pvals, pidx);
    select_msg_kernel<<<B * T / 4, 256, 0, stream>>>(x, q, k, meansum, pvals, pidx,
                                                     gain, bias, plm, pls, out);
}